// Round 11
// baseline (361.822 us; speedup 1.0000x reference)
//
#include <hip/hip_runtime.h>
#include <hip/hip_bf16.h>
#include <cstdint>
#include <cstddef>

typedef unsigned short u16;
typedef unsigned long long u64;
typedef __bf16 bf16x8 __attribute__((ext_vector_type(8)));
typedef float f32x4 __attribute__((ext_vector_type(4)));
typedef unsigned int u32x4 __attribute__((ext_vector_type(4)));

#define EPSF 1e-5f

__device__ __forceinline__ float b2f(u16 u) {
  unsigned int i = ((unsigned int)u) << 16;
  return __builtin_bit_cast(float, i);
}
__device__ __forceinline__ u16 f2b(float f) {
  unsigned int u = __builtin_bit_cast(unsigned int, f);
  u = u + 0x7fffu + ((u >> 16) & 1u);  // round-to-nearest-even
  return (u16)(u >> 16);
}

__device__ __forceinline__ void async_load16(const u16* g, u16* l) {
  __builtin_amdgcn_global_load_lds(
      (__attribute__((address_space(1))) void*)(g),
      (__attribute__((address_space(3))) void*)(l), 16, 0, 0);
}

// ---------------- kernel 1: fused prep (A-convert+deg | build_f | ThT2) ----
// Ft col layout NOW ch-interleaved: col = bp*256 + ch*8 + f  (f fastest) so a
// 128-col GEMM block holds all 8 features for 16 channels.
__global__ __launch_bounds__(256) void prep_kernel(
    const void* __restrict__ X, const void* __restrict__ A,
    const void* __restrict__ Th, u16* __restrict__ Abf, u16* __restrict__ Ft,
    float* __restrict__ deg, float* __restrict__ logd, u16* __restrict__ ThT2) {
  __shared__ int sbad;
  __shared__ float Xl[256 * 13];
  __shared__ float red[4];
  const int tid = threadIdx.x;
  if (tid == 0) sbad = 0;
  __syncthreads();
  {
    const u16* Xu = (const u16*)X;
    int bad = 0;
#pragma unroll
    for (int q = 0; q < 8; ++q) {
      float a = fabsf(b2f(Xu[q * 256 + tid]));
      if (!(a <= 1e4f)) bad = 1;  // huge or NaN -> fp32 storage
    }
    if (bad) atomicOr(&sbad, 1);
  }
  __syncthreads();
  const int isf32 = sbad;
  const int bid = blockIdx.x;

  if (bid < 2048) {
    // ---- role A: convert A row -> bf16 AND compute degree in one pass
    const int row = bid;
    float s = 0.f;
    uint4 st;
    if (isf32) {
      const float4* Af = (const float4*)A + (size_t)row * 512 + tid * 2;
      float4 a = Af[0], b = Af[1];
      s = a.x + a.y + a.z + a.w + b.x + b.y + b.z + b.w;
      u16 o[8] = {f2b(a.x), f2b(a.y), f2b(a.z), f2b(a.w),
                  f2b(b.x), f2b(b.y), f2b(b.z), f2b(b.w)};
      st = *(const uint4*)o;
    } else {
      st = ((const uint4*)A)[(size_t)row * 256 + tid];
      const u16* o = (const u16*)&st;
#pragma unroll
      for (int k = 0; k < 8; ++k) s += b2f(o[k]);
    }
    *(uint4*)(Abf + (size_t)row * 2048 + tid * 8) = st;
#pragma unroll
    for (int off = 32; off > 0; off >>= 1) s += __shfl_down(s, off, 64);
    const int lane = tid & 63, w = tid >> 6;
    if (lane == 0) red[w] = s;
    __syncthreads();
    if (tid == 0) {
      float t = red[0] + red[1] + red[2] + red[3];
      deg[row] = t;
      logd[row] = logf(t + 1.f);
    }
  } else if (bid < 3072) {
    // ---- role B: build F^T with ch-interleaved columns
    const int blk = bid - 2048;      // b*256 + ch*8 + mc
    const int mc = blk & 7;
    const int ch = (blk >> 3) & 31;
    const int b  = blk >> 8;
    const size_t g0 = ((size_t)(b * 32 + ch) * 2048 + (size_t)mc * 256) * 12;
    if (isf32) {
      const float4* Xg = (const float4*)((const float*)X + g0);
#pragma unroll
      for (int q = 0; q < 3; ++q) {
        const int id = q * 256 + tid;        // 0..767 float4s
        const float4 v = Xg[id];
        const int j = id * 4, row = j / 12, col = j % 12;  // col in {0,4,8}
        Xl[row * 13 + col]     = v.x;
        Xl[row * 13 + col + 1] = v.y;
        Xl[row * 13 + col + 2] = v.z;
        Xl[row * 13 + col + 3] = v.w;
      }
    } else {
      const u16* Xg = (const u16*)X + g0;
#pragma unroll
      for (int q = 0; q < 12; ++q) {
        const int id = q * 256 + tid;        // 0..3071 u16s
        Xl[(id / 12) * 13 + id % 12] = b2f(Xg[id]);
      }
    }
    __syncthreads();
    for (int u = tid; u < 384; u += 256) {   // 12 p x 32 m-groups
      const int p = u >> 5;
      const int mg = u & 31;
      float x[8], e[8], en[8];
#pragma unroll
      for (int j = 0; j < 8; ++j) {
        x[j] = Xl[(mg * 8 + j) * 13 + p];
        e[j] = __expf(x[j]);
        en[j] = __expf(-x[j]);
      }
      const size_t cbase = (size_t)(b * 12 + p) * 256 + ch * 8;
      const int gmb = mc * 256 + mg * 8;
#pragma unroll
      for (int f = 0; f < 8; ++f) {
        u16 o[8];
#pragma unroll
        for (int j = 0; j < 8; ++j) {
          const float xx = x[j];
          const float x2 = xx * xx;
          float v;
          if      (f == 0) v = xx;
          else if (f == 1) v = x2;
          else if (f == 2) v = x2 * xx;
          else if (f == 3) v = x2 * x2;
          else if (f == 4) v = xx * e[j];
          else if (f == 5) v = e[j];
          else if (f == 6) v = xx * en[j];
          else             v = en[j];
          o[j] = f2b(v);
        }
        *(uint4*)(Ft + (cbase + f) * 2048 + gmb) = *(const uint4*)o;
      }
    }
  } else {
    // ---- role C: Theta -> ThT2[h][o][352]: kk = (a*16+cl)*3+sc, pad 336..351
    const int e = (bid - 3072) * 256 + tid;  // 84 blocks * 256 = 21504 exactly
    if (e < 21504) {
      const int k = e >> 5, o = e & 31;      // Th row k (672), out col o (32)
      const int sc = k / 224;                // scaler 0..2
      const int r2 = k - sc * 224;
      const int a = r2 >> 5, ch = r2 & 31;
      const int h = ch >> 4, cl = ch & 15;
      const int kk = (a * 16 + cl) * 3 + sc;
      const float v = isf32 ? ((const float*)Th)[e] : b2f(((const u16*)Th)[e]);
      ThT2[(size_t)(h * 32 + o) * 352 + kk] = f2b(v);
    }
    if (bid == 3072) {  // zero the K-pad (disjoint from value writes: no race)
      for (int t = tid; t < 1024; t += 256) {
        const int h = t >> 9, rest = t & 511, o = rest >> 4, kp = 336 + (rest & 15);
        ThT2[(size_t)(h * 32 + o) * 352 + kp] = 0;
      }
    }
  }
}

// ---------------- kernel 2: GEMM + fused moments/scalers/projection --------
// K-loop FROZEN (r9 partition, 103us). After it, each block post-processes
// its own 128x128 C-tile (all 8 features x 16 ch): per 32-node chunk,
// C->LDS bf16, moments+PNA scalers -> feats[32][352] (K=336+pad), 11-MFMA
// projection vs ThT2 half, coalesced f32 partial store to Yp[h][bp][o][i].
__global__ __launch_bounds__(256) void gemm_fused_kernel(
    const u16* __restrict__ A, const u16* __restrict__ Ft,
    const float* __restrict__ deg, const float* __restrict__ logd,
    const u16* __restrict__ ThT2, float* __restrict__ Yp) {
  __shared__ __attribute__((aligned(16))) u16 smem[2 * 128 * 64];  // 32 KB
  __shared__ float red4[4];
  u16* As = smem;             // [128][64]
  u16* Bs = smem + 128 * 64;  // [128][64]
  const int tid = threadIdx.x;
  const int wave = tid >> 6;
  const int lane = tid & 63;
  const int l15 = lane & 15;
  const int quad = lane >> 4;
  const int wm = wave >> 1;
  const int wn = wave & 1;

  // delta = mean(logd) — reduced in-block before staging begins
  float ls = 0.f;
#pragma unroll
  for (int q = 0; q < 8; ++q) ls += logd[q * 256 + tid];
#pragma unroll
  for (int off = 32; off > 0; off >>= 1) ls += __shfl_down(ls, off, 64);
  if ((tid & 63) == 0) red4[tid >> 6] = ls;
  __syncthreads();
  const float delta = (red4[0] + red4[1] + red4[2] + red4[3]) * (1.0f / 2048.0f);

  const int i4 = blockIdx.x;         // 0..1535
  const int xcd = i4 & 7;
  const int s4 = i4 >> 3;
  const int bm = (xcd >> 1) * 4 + (s4 & 3);
  const int bn = (xcd & 1) * 48 + (s4 >> 2);
  const int h  = bn & 1;             // ch-half
  const int bp = bn >> 1;            // 0..47

  const int lrow = lane >> 3;
  const int schunk = (lane & 7) ^ lrow;
  const u16* gA = A  + (size_t)(bm * 128 + wave * 32 + lrow) * 2048 + schunk * 8;
  const u16* gB = Ft + (size_t)(bn * 128 + wave * 32 + lrow) * 2048 + schunk * 8;
  u16* lA = As + wave * 32 * 64 + lane * 8;
  u16* lB = Bs + wave * 32 * 64 + lane * 8;

  f32x4 acc[4][4];
#pragma unroll
  for (int i = 0; i < 4; ++i)
#pragma unroll
    for (int j = 0; j < 4; ++j) acc[i][j] = (f32x4){0.f, 0.f, 0.f, 0.f};

  for (int kk = 0; kk < 2048; kk += 64) {
    __syncthreads();
#pragma unroll
    for (int i = 0; i < 4; ++i) {
      async_load16(gA + (size_t)i * (8 * 2048) + kk, lA + i * (8 * 64));
      async_load16(gB + (size_t)i * (8 * 2048) + kk, lB + i * (8 * 64));
    }
    __syncthreads();
#pragma unroll
    for (int ks = 0; ks < 2; ++ks) {
      const int ca = ((ks * 4 + quad) ^ (l15 & 7)) * 8;
      bf16x8 af[4], bfr[4];
#pragma unroll
      for (int t = 0; t < 4; ++t)
        af[t] = *(const bf16x8*)(As + (wm * 64 + t * 16 + l15) * 64 + ca);
#pragma unroll
      for (int t = 0; t < 4; ++t)
        bfr[t] = *(const bf16x8*)(Bs + (wn * 64 + t * 16 + l15) * 64 + ca);
#pragma unroll
      for (int mt = 0; mt < 4; ++mt)
#pragma unroll
        for (int nt = 0; nt < 4; ++nt)
          acc[mt][nt] = __builtin_amdgcn_mfma_f32_16x16x32_bf16(af[mt], bfr[nt],
                                                                acc[mt][nt], 0, 0, 0);
    }
  }
  __syncthreads();  // K-loop LDS reads done; smem now reused for epilogue

  // LDS overlay: Cs32 [32][144] u16 (9216 B) + feats [32][352] u16 (22528 B)
  u16* Cs32 = smem;
  u16* feats = smem + 32 * 144;
  // zero feats K-pad (kk 336..351) once — stays 0 across chunks
#pragma unroll
  for (int t = 0; t < 2; ++t) {
    const int id = t * 256 + tid;  // 0..511 = 32 nodes x 16 pads
    feats[(id >> 4) * 352 + 336 + (id & 15)] = 0;
  }

  const int mt2 = wave >> 1, nt2 = wave & 1;  // projection quadrant
  const int oo = nt2 * 16 + l15;

#pragma unroll
  for (int c = 0; c < 4; ++c) {
    // --- C-tile chunk (rows c*32..c*32+31) -> Cs32 bf16 (2 of 4 waves)
    if (wm == (c >> 1)) {
#pragma unroll
      for (int mtl = 0; mtl < 2; ++mtl) {
        const int mt = 2 * (c & 1) + mtl;
#pragma unroll
        for (int nt = 0; nt < 4; ++nt) {
          const int col = wn * 64 + nt * 16 + l15;
#pragma unroll
          for (int j = 0; j < 4; ++j) {
            const int lr = mtl * 16 + quad * 4 + j;
            float v;
            if (mt == 0) v = acc[0][nt][j];
            else if (mt == 1) v = acc[1][nt][j];
            else if (mt == 2) v = acc[2][nt][j];
            else v = acc[3][nt][j];
            Cs32[lr * 144 + col] = f2b(v);
          }
        }
      }
    }
    __syncthreads();
    // --- moments + scalers -> feats (2 (node,ch) pairs per thread)
#pragma unroll
    for (int t = 0; t < 2; ++t) {
      const int pt = t * 256 + tid;        // 0..511
      const int n32 = pt >> 4, cl = pt & 15;
      const int gi = bm * 128 + c * 32 + n32;
      const float rd = 1.0f / fmaxf(deg[gi], EPSF);
      const float s = logd[gi] / delta;
      const float is = 1.0f / fmaxf(s, EPSF);
      const u16* cr = Cs32 + n32 * 144 + cl * 8;   // 8 features, b128 read
      uint4 cv = *(const uint4*)cr;
      const u16* cu = (const u16*)&cv;
      const float m1 = b2f(cu[0]) * rd;
      const float m2 = b2f(cu[1]) * rd;
      const float m3 = b2f(cu[2]) * rd;
      const float m4 = b2f(cu[3]) * rd;
      const float smx = b2f(cu[4]) / (b2f(cu[5]) + EPSF);
      const float smn = b2f(cu[6]) / (b2f(cu[7]) + EPSF);
      const float x = b2f(Ft[(size_t)(bn * 128 + cl * 8) * 2048 + gi]);  // identity feat
      const float var = fmaxf(m2 - m1 * m1, 0.f);
      const float stdv = sqrtf(var + EPSF);
      const float x2 = x * x, x3 = x2 * x, x4 = x2 * x2;
      const float dist = x2 - 2.f * x * m1 + m2;
      const float ed2 = x4 - 4.f * x3 * m1 + 6.f * x2 * m2 - 4.f * x * m3 + m4;
      const float dstd = sqrtf(fmaxf(ed2 - dist * dist, 0.f) + EPSF);
      const float f7[7] = {smn, smx, m1, stdv, var, dist, dstd};
#pragma unroll
      for (int a = 0; a < 7; ++a) {
        const int kk = (a * 16 + cl) * 3;
        const float v = f7[a];
        feats[n32 * 352 + kk]     = f2b(v);
        feats[n32 * 352 + kk + 1] = f2b(v * s);
        feats[n32 * 352 + kk + 2] = f2b(v * is);
      }
    }
    __syncthreads();
    // --- projection: 32 nodes x 32 outs, K=352 (11 MFMA), all 4 waves
    f32x4 pacc = (f32x4){0.f, 0.f, 0.f, 0.f};
#pragma unroll
    for (int kt = 0; kt < 11; ++kt) {
      bf16x8 a  = *(const bf16x8*)(feats + (mt2 * 16 + l15) * 352 + kt * 32 + quad * 8);
      bf16x8 bb = *(const bf16x8*)(ThT2 + (size_t)(h * 32 + oo) * 352 + kt * 32 + quad * 8);
      pacc = __builtin_amdgcn_mfma_f32_16x16x32_bf16(a, bb, pacc, 0, 0, 0);
    }
    const int ibase = bm * 128 + c * 32 + mt2 * 16 + quad * 4;
    __builtin_nontemporal_store(pacc,
        (f32x4*)(Yp + ((size_t)(h * 48 + bp) * 32 + oo) * 2048 + ibase));
    __syncthreads();  // feats/Cs32 reads done before next chunk overwrites
  }
}

// ---------------- kernel 3: sum halves + bias + leaky + transpose-out ------
// block = (b, o, iq): reads Yp[0/1][b*12+p][o][iq*512..] coalesced, LDS
// transpose, writes out[(b*32+o)*2048 + i][p] as contiguous 24 KB.
__global__ __launch_bounds__(256) void transpose_kernel(
    const float* __restrict__ Yp, const void* __restrict__ Bias,
    void* __restrict__ out, const u16* __restrict__ Xu) {
  __shared__ float T[512 * 13];
  __shared__ int sbad;
  const int tid = threadIdx.x;
  if (tid == 0) sbad = 0;
  __syncthreads();
  {
    int bad = 0;
#pragma unroll
    for (int q = 0; q < 8; ++q) {
      float a = fabsf(b2f(Xu[q * 256 + tid]));
      if (!(a <= 1e4f)) bad = 1;
    }
    if (bad) atomicOr(&sbad, 1);
  }
  __syncthreads();
  const int isf32 = sbad;

  const int bid = blockIdx.x;        // 0..511
  const int iq = bid & 3;
  const int o  = (bid >> 2) & 31;
  const int b  = bid >> 7;
  const float bias = isf32 ? ((const float*)Bias)[o] : b2f(((const u16*)Bias)[o]);

#pragma unroll
  for (int p = 0; p < 12; ++p) {
    const size_t base0 = ((size_t)((b * 12 + p)) * 32 + o) * 2048 + iq * 512;
    const size_t base1 = ((size_t)(48 + b * 12 + p) * 32 + o) * 2048 + iq * 512;
#pragma unroll
    for (int t = 0; t < 2; ++t) {
      const int ii = t * 256 + tid;
      T[ii * 13 + p] = Yp[base0 + ii] + Yp[base1 + ii];
    }
  }
  __syncthreads();
  const size_t ob = ((size_t)(b * 32 + o) * 2048 + iq * 512) * 12;
#pragma unroll
  for (int t = 0; t < 2; ++t) {
    const int r2 = tid * 2 + t;        // local i row 0..511
    float v[12];
#pragma unroll
    for (int p = 0; p < 12; ++p) {
      float x = T[r2 * 13 + p] + bias;
      v[p] = x > 0.f ? x : 0.01f * x;  // leaky_relu
    }
    if (isf32) {
      float* dst = (float*)out + ob + (size_t)r2 * 12;
      *(float4*)(dst)     = (float4){v[0], v[1], v[2], v[3]};
      *(float4*)(dst + 4) = (float4){v[4], v[5], v[6], v[7]};
      *(float4*)(dst + 8) = (float4){v[8], v[9], v[10], v[11]};
    } else {
      u16* dst = (u16*)out + ob + (size_t)r2 * 12;
#pragma unroll
      for (int p = 0; p < 12; ++p) dst[p] = f2b(v[p]);
    }
  }
}

// ---------------------------------------------------------------------------
extern "C" void kernel_launch(void* const* d_in, const int* in_sizes, int n_in,
                              void* d_out, int out_size, void* d_ws, size_t ws_size,
                              hipStream_t stream) {
  const void* X    = d_in[0];
  const void* A    = d_in[1];
  const void* Th   = d_in[2];
  const void* Bias = d_in[3];
  char* ws = (char*)d_ws;

  u16*   Ft   = (u16*)(ws);                      // 12288*2048*2 = 50331648
  float* Yp   = (float*)(ws + 50331648);         // 2*48*32*2048*4 = 25165824
  u16*   Abf  = (u16*)(ws + 75497472);           // 8388608
  float* deg  = (float*)(ws + 83886080);         // 8192
  float* logd = (float*)(ws + 83894272);         // 8192
  u16*   ThT2 = (u16*)(ws + 83902464);           // 2*32*352*2 = 45056

  prep_kernel<<<3156, 256, 0, stream>>>(X, A, Th, Abf, Ft, deg, logd, ThT2);
  gemm_fused_kernel<<<1536, 256, 0, stream>>>(Abf, Ft, deg, logd, ThT2, Yp);
  transpose_kernel<<<512, 256, 0, stream>>>(Yp, Bias, d_out, (const u16*)X);
}

// Round 12
// 214.757 us; speedup vs baseline: 1.6848x; 1.6848x over previous
//
#include <hip/hip_runtime.h>
#include <hip/hip_bf16.h>
#include <cstdint>
#include <cstddef>

typedef unsigned short u16;
typedef __bf16 bf16x8 __attribute__((ext_vector_type(8)));
typedef float f32x4 __attribute__((ext_vector_type(4)));
typedef unsigned int u32x4 __attribute__((ext_vector_type(4)));  // clang vec: ok for nontemporal builtins

#define EPSF 1e-5f

__device__ __forceinline__ float b2f(u16 u) {
  unsigned int i = ((unsigned int)u) << 16;
  return __builtin_bit_cast(float, i);
}
__device__ __forceinline__ u16 f2b(float f) {
  unsigned int u = __builtin_bit_cast(unsigned int, f);
  u = u + 0x7fffu + ((u >> 16) & 1u);  // round-to-nearest-even
  return (u16)(u >> 16);
}

// async global->LDS, 16B/lane.
__device__ __forceinline__ void async_load16(const u16* g, u16* l) {
  __builtin_amdgcn_global_load_lds(
      (__attribute__((address_space(1))) void*)(g),
      (__attribute__((address_space(3))) void*)(l), 16, 0, 0);
}

// ---------------- kernel 1: fused prep (A-convert+deg | build_f | thetaT) --
__global__ __launch_bounds__(256) void prep_kernel(
    const void* __restrict__ X, const void* __restrict__ A,
    const void* __restrict__ Th, u16* __restrict__ Abf, u16* __restrict__ Ft,
    float* __restrict__ deg, float* __restrict__ logd, u16* __restrict__ ThT) {
  __shared__ int sbad;
  __shared__ float Xl[256 * 13];
  __shared__ float red[4];
  const int tid = threadIdx.x;
  if (tid == 0) sbad = 0;
  __syncthreads();
  {
    const u16* Xu = (const u16*)X;
    int bad = 0;
#pragma unroll
    for (int q = 0; q < 8; ++q) {
      float a = fabsf(b2f(Xu[q * 256 + tid]));
      if (!(a <= 1e4f)) bad = 1;  // huge or NaN
    }
    if (bad) atomicOr(&sbad, 1);
  }
  __syncthreads();
  const int isf32 = sbad;
  const int bid = blockIdx.x;

  if (bid < 2048) {
    // ---- role A: convert A row -> bf16 AND compute degree in one pass
    const int row = bid;
    float s = 0.f;
    uint4 st;
    if (isf32) {
      const float4* Af = (const float4*)A + (size_t)row * 512 + tid * 2;
      float4 a = Af[0], b = Af[1];
      s = a.x + a.y + a.z + a.w + b.x + b.y + b.z + b.w;
      u16 o[8] = {f2b(a.x), f2b(a.y), f2b(a.z), f2b(a.w),
                  f2b(b.x), f2b(b.y), f2b(b.z), f2b(b.w)};
      st = *(const uint4*)o;
    } else {
      st = ((const uint4*)A)[(size_t)row * 256 + tid];
      const u16* o = (const u16*)&st;
#pragma unroll
      for (int k = 0; k < 8; ++k) s += b2f(o[k]);
    }
    *(uint4*)(Abf + (size_t)row * 2048 + tid * 8) = st;
#pragma unroll
    for (int off = 32; off > 0; off >>= 1) s += __shfl_down(s, off, 64);
    const int lane = tid & 63, w = tid >> 6;
    if (lane == 0) red[w] = s;
    __syncthreads();
    if (tid == 0) {
      float t = red[0] + red[1] + red[2] + red[3];
      deg[row] = t;
      logd[row] = logf(t + 1.f);
    }
  } else if (bid < 3072) {
    // ---- role B: build F^T [12288][2048] bf16
    const int blk = bid - 2048;      // b*256 + ch*8 + mc
    const int mc = blk & 7;
    const int ch = (blk >> 3) & 31;
    const int b  = blk >> 8;
    const size_t g0 = ((size_t)(b * 32 + ch) * 2048 + (size_t)mc * 256) * 12;
    if (isf32) {
      const float4* Xg = (const float4*)((const float*)X + g0);
#pragma unroll
      for (int q = 0; q < 3; ++q) {
        const int id = q * 256 + tid;        // 0..767 float4s
        const float4 v = Xg[id];
        const int j = id * 4, row = j / 12, col = j % 12;  // col in {0,4,8}
        Xl[row * 13 + col]     = v.x;
        Xl[row * 13 + col + 1] = v.y;
        Xl[row * 13 + col + 2] = v.z;
        Xl[row * 13 + col + 3] = v.w;
      }
    } else {
      const u16* Xg = (const u16*)X + g0;
#pragma unroll
      for (int q = 0; q < 12; ++q) {
        const int id = q * 256 + tid;        // 0..3071 u16s
        Xl[(id / 12) * 13 + id % 12] = b2f(Xg[id]);
      }
    }
    __syncthreads();
    const int m = tid;
    const int gm = mc * 256 + m;
#pragma unroll
    for (int p = 0; p < 12; ++p) {
      const float x = Xl[m * 13 + p];
      const float x2 = x * x, x3 = x2 * x, x4 = x2 * x2;
      const float e = __expf(x), en = __expf(-x);
      const float vals[8] = {x, x2, x3, x4, x * e, e, x * en, en};
      const size_t cb = (size_t)(b * 12 + p) * 256 + ch;
#pragma unroll
      for (int f = 0; f < 8; ++f)
        Ft[(cb + (size_t)f * 32) * 2048 + gm] = f2b(vals[f]);
    }
  } else {
    // ---- role C: Theta transpose -> ThT [32][672]
    const int e = (bid - 3072) * 256 + tid;
    if (e < 21504) {
      const int k = e >> 5, o = e & 31;
      ThT[o * 672 + k] = isf32 ? f2b(((const float*)Th)[e]) : ((const u16*)Th)[e];
    }
  }
}

// ---------------- kernel 2: GEMM Y = Abf @ F (FROZEN r9: ~105us, ~963TF) ---
// XCD partition: 4 bm x 48 bn rectangle per XCD, bm-fastest -> FETCH 117MB.
__global__ __launch_bounds__(256) void gemm_kernel(const u16* __restrict__ A,
                                                   const u16* __restrict__ Ft,
                                                   u16* __restrict__ Y) {
  __shared__ __attribute__((aligned(16))) u16 smem[2 * 128 * 64];  // 32 KB
  u16* As = smem;             // [128][64]
  u16* Bs = smem + 128 * 64;  // [128][64]
  const int tid = threadIdx.x;
  const int wave = tid >> 6;
  const int lane = tid & 63;
  const int l15 = lane & 15;
  const int quad = lane >> 4;
  const int wm = wave >> 1;
  const int wn = wave & 1;

  const int i4 = blockIdx.x;         // 0..1535
  const int xcd = i4 & 7;
  const int s4 = i4 >> 3;            // 0..191
  const int bm = (xcd >> 1) * 4 + (s4 & 3);
  const int bn = (xcd & 1) * 48 + (s4 >> 2);

  const int lrow = lane >> 3;                    // 0..7
  const int schunk = (lane & 7) ^ lrow;          // swizzled source chunk
  const u16* gA = A  + (size_t)(bm * 128 + wave * 32 + lrow) * 2048 + schunk * 8;
  const u16* gB = Ft + (size_t)(bn * 128 + wave * 32 + lrow) * 2048 + schunk * 8;
  u16* lA = As + wave * 32 * 64 + lane * 8;  // per-lane dest (base + lane*16B)
  u16* lB = Bs + wave * 32 * 64 + lane * 8;

  f32x4 acc[4][4];
#pragma unroll
  for (int i = 0; i < 4; ++i)
#pragma unroll
    for (int j = 0; j < 4; ++j) acc[i][j] = (f32x4){0.f, 0.f, 0.f, 0.f};

  for (int kk = 0; kk < 2048; kk += 64) {
    __syncthreads();  // prev iter's LDS reads done before overwrite
#pragma unroll
    for (int i = 0; i < 4; ++i) {
      async_load16(gA + (size_t)i * (8 * 2048) + kk, lA + i * (8 * 64));
      async_load16(gB + (size_t)i * (8 * 2048) + kk, lB + i * (8 * 64));
    }
    __syncthreads();  // compiler drains vmcnt(0) before s_barrier
#pragma unroll
    for (int ks = 0; ks < 2; ++ks) {
      const int ca = ((ks * 4 + quad) ^ (l15 & 7)) * 8;  // un-swizzle chunk
      bf16x8 af[4], bfr[4];
#pragma unroll
      for (int t = 0; t < 4; ++t)
        af[t] = *(const bf16x8*)(As + (wm * 64 + t * 16 + l15) * 64 + ca);
#pragma unroll
      for (int t = 0; t < 4; ++t)
        bfr[t] = *(const bf16x8*)(Bs + (wn * 64 + t * 16 + l15) * 64 + ca);
#pragma unroll
      for (int mt = 0; mt < 4; ++mt)
#pragma unroll
        for (int nt = 0; nt < 4; ++nt)
          acc[mt][nt] = __builtin_amdgcn_mfma_f32_16x16x32_bf16(af[mt], bfr[nt],
                                                                acc[mt][nt], 0, 0, 0);
    }
  }

  __syncthreads();  // all K-loop LDS reads complete before aliasing
  u16* Cs = smem;   // [128][128] u16 = 32 KB
#pragma unroll
  for (int mt = 0; mt < 4; ++mt)
#pragma unroll
    for (int nt = 0; nt < 4; ++nt) {
      const int row = wm * 64 + mt * 16 + quad * 4;
      const int col = wn * 64 + nt * 16 + l15;
#pragma unroll
      for (int j = 0; j < 4; ++j)
        Cs[(row + j) * 128 + col] = f2b(acc[mt][nt][j]);
    }
  __syncthreads();
  const size_t ybase = (size_t)(bm * 128) * 12288 + (size_t)bn * 128;
#pragma unroll
  for (int q = 0; q < 8; ++q) {
    const int id = q * 256 + tid;           // 0..2047
    const int r = id >> 4, c = (id & 15) * 8;
    __builtin_nontemporal_store(*(const u32x4*)(Cs + r * 128 + c),
                                (u32x4*)(Y + ybase + (size_t)r * 12288 + c));
  }
}

// ---------------- kernel 3: epilogue v3 + self-detect + self-delta ---------
__global__ __launch_bounds__(256) void epilogue_kernel(
    const u16* __restrict__ Y, const u16* __restrict__ Fx,
    const float* __restrict__ deg, const float* __restrict__ logd,
    const u16* __restrict__ ThT, const void* __restrict__ Bias,
    void* __restrict__ out, const u16* __restrict__ Xu) {
  __shared__ __attribute__((aligned(16))) u16 Ys[32 * 264];
  __shared__ u16 Xs[32 * 33];
  __shared__ __attribute__((aligned(16))) u16 feats[32 * 680];
  __shared__ int sbad;
  __shared__ float red[4];
  const int tid = threadIdx.x;
  if (tid == 0) sbad = 0;
  __syncthreads();
  float ls = 0.f;
  {
    int bad = 0;
#pragma unroll
    for (int q = 0; q < 8; ++q) {
      float a = fabsf(b2f(Xu[q * 256 + tid]));
      if (!(a <= 1e4f)) bad = 1;
      ls += logd[q * 256 + tid];
    }
    if (bad) atomicOr(&sbad, 1);
  }
#pragma unroll
  for (int off = 32; off > 0; off >>= 1) ls += __shfl_down(ls, off, 64);
  if ((tid & 63) == 0) red[tid >> 6] = ls;
  __syncthreads();
  const int isf32 = sbad;
  const float delta = (red[0] + red[1] + red[2] + red[3]) * (1.0f / 2048.0f);

  const int nc = blockIdx.x;   // 0..63 node chunk
  const int b  = blockIdx.y;   // 0..3
  const int pz = blockIdx.z;   // 0..1

  const int nl = tid >> 3;     // 0..31 local node
  const int chg = tid & 7;     // 4 channels each
  const int inode = nc * 32 + nl;
  const float d = fmaxf(deg[inode], EPSF);
  const float rd = 1.0f / d;
  const float s = logd[inode] / delta;
  const float is = 1.0f / fmaxf(s, EPSF);

  const int wave = tid >> 6, lane = tid & 63;
  const int l15 = lane & 15, quad = lane >> 4;
  const int mt = wave >> 1, nt = wave & 1;  // 2x2 of 16x16
  const int o = nt * 16 + l15;
  const float bias = isf32 ? ((const float*)Bias)[o] : b2f(((const u16*)Bias)[o]);

  float r[4][6];

#pragma unroll
  for (int pp = 0; pp < 6; ++pp) {
    const int p = pz * 6 + pp;
    const int bp = b * 12 + p;
    __syncthreads();  // prior iter's LDS reads complete
#pragma unroll
    for (int q = 0; q < 4; ++q) {
      const int id = q * 256 + tid;                 // 0..1023
      const int rr = id >> 5, ck = id & 31;
      *(u32x4*)(Ys + rr * 264 + ck * 8) = __builtin_nontemporal_load(
          (const u32x4*)(Y + (size_t)(nc * 32 + rr) * 12288 + (size_t)bp * 256 + ck * 8));
      Xs[rr * 33 + ck] = Fx[(size_t)(bp * 256 + rr) * 2048 + nc * 32 + ck];
    }
    __syncthreads();

    const u16* yr = Ys + nl * 264;
#pragma unroll
    for (int cc = 0; cc < 4; ++cc) {
      const int ch = chg * 4 + cc;
      const float m1 = b2f(yr[ch]) * rd;
      const float m2 = b2f(yr[32 + ch]) * rd;
      const float m3 = b2f(yr[64 + ch]) * rd;
      const float m4 = b2f(yr[96 + ch]) * rd;
      const float smx = b2f(yr[128 + ch]) / (b2f(yr[160 + ch]) + EPSF);
      const float smn = b2f(yr[192 + ch]) / (b2f(yr[224 + ch]) + EPSF);
      const float x = b2f(Xs[ch * 33 + nl]);
      const float var = fmaxf(m2 - m1 * m1, 0.f);
      const float stdv = sqrtf(var + EPSF);
      const float x2 = x * x, x3 = x2 * x, x4 = x2 * x2;
      const float dist = x2 - 2.f * x * m1 + m2;
      const float ed2 = x4 - 4.f * x3 * m1 + 6.f * x2 * m2 - 4.f * x * m3 + m4;
      const float dstd = sqrtf(fmaxf(ed2 - dist * dist, 0.f) + EPSF);
      const float f7[7] = {smn, smx, m1, stdv, var, dist, dstd};
#pragma unroll
      for (int a = 0; a < 7; ++a) {
        const int k = a * 32 + ch;
        feats[nl * 680 + k]       = f2b(f7[a]);
        feats[nl * 680 + 224 + k] = f2b(f7[a] * s);
        feats[nl * 680 + 448 + k] = f2b(f7[a] * is);
      }
    }
    __syncthreads();

    f32x4 acc = (f32x4){0.f, 0.f, 0.f, 0.f};
#pragma unroll
    for (int kt = 0; kt < 21; ++kt) {  // K = 672
      bf16x8 a  = *(const bf16x8*)(feats + (mt * 16 + l15) * 680 + kt * 32 + quad * 8);
      bf16x8 bb = *(const bf16x8*)(ThT + (size_t)o * 672 + kt * 32 + quad * 8);
      acc = __builtin_amdgcn_mfma_f32_16x16x32_bf16(a, bb, acc, 0, 0, 0);
    }
#pragma unroll
    for (int j = 0; j < 4; ++j) r[j][pp] = acc[j];
  }

#pragma unroll
  for (int j = 0; j < 4; ++j) {
    const int node = mt * 16 + quad * 4 + j;
    const int ig = nc * 32 + node;
    const size_t oi = ((size_t)(b * 32 + o) * 2048 + ig) * 12 + pz * 6;
    float v[6];
#pragma unroll
    for (int k = 0; k < 6; ++k) {
      float t = r[j][k] + bias;
      v[k] = t > 0.f ? t : 0.01f * t;   // leaky_relu
    }
    if (isf32) {
      float* dst = (float*)out + oi;   // 8B-aligned
      *(float2*)(dst)     = (float2){v[0], v[1]};
      *(float2*)(dst + 2) = (float2){v[2], v[3]};
      *(float2*)(dst + 4) = (float2){v[4], v[5]};
    } else {
      u16* dst = (u16*)out + oi;
#pragma unroll
      for (int k = 0; k < 6; ++k) dst[k] = f2b(v[k]);
    }
  }
}

// ---------------------------------------------------------------------------
extern "C" void kernel_launch(void* const* d_in, const int* in_sizes, int n_in,
                              void* d_out, int out_size, void* d_ws, size_t ws_size,
                              hipStream_t stream) {
  const void* X    = d_in[0];
  const void* A    = d_in[1];
  const void* Th   = d_in[2];
  const void* Bias = d_in[3];
  char* ws = (char*)d_ws;

  u16*   Ft   = (u16*)(ws);                       // 12288*2048*2 = 50331648
  u16*   Y    = (u16*)(ws + 50331648);            // 2048*12288*2 = 50331648
  u16*   Abf  = (u16*)(ws + 100663296);           // 2048*2048*2  = 8388608
  float* deg  = (float*)(ws + 109051904);         // 8192
  float* logd = (float*)(ws + 109060096);         // 8192
  u16*   ThT  = (u16*)(ws + 109068288);           // 43008

  prep_kernel<<<3156, 256, 0, stream>>>(X, A, Th, Abf, Ft, deg, logd, ThT);
  gemm_kernel<<<1536, 256, 0, stream>>>(Abf, Ft, Y);
  epilogue_kernel<<<dim3(64, 4, 2), 256, 0, stream>>>(Y, Ft, deg, logd, ThT,
                                                      Bias, d_out, (const u16*)X);
}